// Round 3
// baseline (650.600 us; speedup 1.0000x reference)
//
#include <hip/hip_runtime.h>
#include <math.h>

// out[b,h,p,n] = sum_t exp(Total(b,h) - P[t]) * X[b,t,h,p] * B[b,t,h,n]
// P = inclusive prefix sum of A over t (telescoped chunked scan; verified R1/R2).
// Shapes fixed: b=8, s=4096, h=16, p=n=64.

constexpr int Bn = 8;
constexpr int S  = 4096;
constexpr int H  = 16;
constexpr int SEG  = 128;       // prefix segment length
constexpr int NSEG = S / SEG;   // 32
constexpr int SC  = 8;          // superchunks per pair
constexpr int TPB = S / SC;     // 512 t per block
constexpr int TB  = 32;         // t per LDS stage
constexpr int NST = TPB / TB;   // 16 stages

#define AS1 __attribute__((address_space(1)))
#define AS3 __attribute__((address_space(3)))

static __device__ __forceinline__ void g2lds16(const float* g, float* l) {
  __builtin_amdgcn_global_load_lds((const AS1 unsigned int*)g, (AS3 unsigned int*)l, 16, 0, 0);
}
static __device__ __forceinline__ void g2lds4(const float* g, float* l) {
  __builtin_amdgcn_global_load_lds((const AS1 unsigned int*)g, (AS3 unsigned int*)l, 4, 0, 0);
}

// ---------- K1: per-(bb,seg) local prefix of A + segment sums (coalesced) ----------
// Plb[pair*S + t] = inclusive prefix of A within t's 128-segment; ss[bb][seg][h] = segment sum.
__global__ __launch_bounds__(256) void scanA(const float* __restrict__ A,
                                             float* __restrict__ Plb,
                                             float* __restrict__ ss) {
  __shared__ float Al[SEG * 17];   // [t][h] padded (stride 17)
  __shared__ float sp[16][17];
  const int bb = blockIdx.x >> 5, seg = blockIdx.x & 31;
  const int tid = threadIdx.x;
  const float* src = A + ((size_t)bb * S + (size_t)seg * SEG) * H;
  #pragma unroll
  for (int k = 0; k < 2; ++k) {                 // 512 float4, coalesced
    const int f = tid + k * 256;
    const float4 v = ((const float4*)src)[f];
    const int t = f >> 2, h0 = (f & 3) * 4;
    Al[t * 17 + h0 + 0] = v.x; Al[t * 17 + h0 + 1] = v.y;
    Al[t * 17 + h0 + 2] = v.z; Al[t * 17 + h0 + 3] = v.w;
  }
  __syncthreads();
  const int h = tid >> 4, j = tid & 15;         // thread (h, j): t-strip j*8..j*8+8
  float vals[8], run = 0.f;
  #pragma unroll
  for (int k = 0; k < 8; ++k) { run += Al[(j * 8 + k) * 17 + h]; vals[k] = run; }
  sp[h][j] = run;
  __syncthreads();
  float pre = 0.f, tot = 0.f;
  #pragma unroll
  for (int jj = 0; jj < 16; ++jj) { const float x = sp[h][jj]; tot += x; if (jj < j) pre += x; }
  if (j == 0) ss[((size_t)bb * NSEG + seg) * H + h] = tot;
  float* Wp = Plb + ((size_t)(bb * H + h)) * S + seg * SEG + j * 8;
  *(float4*)(Wp)     = make_float4(pre + vals[0], pre + vals[1], pre + vals[2], pre + vals[3]);
  *(float4*)(Wp + 4) = make_float4(pre + vals[4], pre + vals[5], pre + vals[6], pre + vals[7]);
}

// ---------- K2: double-buffered staged outer-product accumulation ----------
__global__ __launch_bounds__(256, 4) void outer_k(const float* __restrict__ X,
                                                  const float* __restrict__ Bm,
                                                  const float* __restrict__ Plb,
                                                  const float* __restrict__ ss,
                                                  float* __restrict__ out) {
  // smem carve: Xs[2][2048] | Bs[2][2048] | Pl[2][64]   (33.3 KB)
  __shared__ float smem[4096 + 4096 + 128];
  float* Xs = smem;
  float* Bs = smem + 4096;
  float* Pl = smem + 8192;

  const int blk = blockIdx.x;
  const int pair = blk >> 3, sc = blk & 7;
  const int bb = pair >> 4, hh = pair & 15;
  const int tid = threadIdx.x, w = tid >> 6, lane = tid & 63;
  const int tstart = sc * TPB;
  const int r = lane >> 3, c = lane & 7;        // 8x8 lane grid -> p0=r*8, n0=c*8

  // wave-register scan of 32 segment sums -> exclusive prefix (lane=seg) + total
  float segv = (lane < NSEG) ? ss[((size_t)bb * NSEG + lane) * H + hh] : 0.f;
  float incl = segv;
  #pragma unroll
  for (int off = 1; off < NSEG; off <<= 1) {
    const float u = __shfl_up(incl, off, 64);
    if (lane >= off) incl += u;
  }
  const float tot = __shfl(incl, NSEG - 1, 64);
  const float pe  = incl - segv;                // exclusive prefix, valid for lane<32

  constexpr size_t RS = (size_t)H * 64;         // 1024 floats per t
  const float* Xb = X  + (((size_t)bb * S + tstart) * H + hh) * 64;
  const float* Bb = Bm + (((size_t)bb * S + tstart) * H + hh) * 64;
  const float* Pb = Plb + (size_t)pair * S + tstart;

  float acc[8][8];
  #pragma unroll
  for (int i = 0; i < 8; ++i)
    #pragma unroll
    for (int j = 0; j < 8; ++j) acc[i][j] = 0.f;

  // ---- stage issue: wave w loads rows w*8..w*8+8 of X and B, wave 0 loads Pl ----
  #define ISSUE(s_, buf_) do {                                                  \
    const size_t tg = (size_t)((s_) * TB + w * 8) * RS;                         \
    float* dx = Xs + (buf_) * 2048 + w * 512;                                   \
    float* db = Bs + (buf_) * 2048 + w * 512;                                   \
    _Pragma("unroll")                                                           \
    for (int k = 0; k < 2; ++k) {                                               \
      const int f = k * 64 + lane;                                              \
      const size_t go = tg + (size_t)(f >> 4) * RS + (size_t)(f & 15) * 4;      \
      g2lds16(Xb + go, dx + k * 256);                                           \
      g2lds16(Bb + go, db + k * 256);                                           \
    }                                                                           \
    if (w == 0) g2lds4(Pb + (s_) * TB + (lane & 31), Pl + (buf_) * 64);         \
  } while (0)

  ISSUE(0, 0);
  for (int s = 0; s < NST; ++s) {
    __syncthreads();                    // stage s resident; prev compute done
    if (s + 1 < NST) ISSUE(s + 1, (s + 1) & 1);
    // decay offset for this stage's 128-seg
    const int seg = (tstart + s * TB) >> 7;
    const float cm = tot - __shfl(pe, seg, 64);
    const float* xb = Xs + (s & 1) * 2048;
    const float* bv = Bs + (s & 1) * 2048;
    const float* pl = Pl + (s & 1) * 64;
    #pragma unroll
    for (int it = 0; it < 8; ++it) {
      const int tt = it * 4 + w;                // wave w consumes tt ≡ w (mod 4)
      const float wgt = __expf(cm - pl[tt]);    // exp(Total - P[t]) <= 1
      const float4 x0 = *(const float4*)(xb + tt * 64 + r * 8);
      const float4 x1 = *(const float4*)(xb + tt * 64 + r * 8 + 4);
      const float4 b0 = *(const float4*)(bv + tt * 64 + c * 8);
      const float4 b1 = *(const float4*)(bv + tt * 64 + c * 8 + 4);
      const float xs[8] = {x0.x * wgt, x0.y * wgt, x0.z * wgt, x0.w * wgt,
                           x1.x * wgt, x1.y * wgt, x1.z * wgt, x1.w * wgt};
      const float bs[8] = {b0.x, b0.y, b0.z, b0.w, b1.x, b1.y, b1.z, b1.w};
      #pragma unroll
      for (int i = 0; i < 8; ++i)
        #pragma unroll
        for (int j = 0; j < 8; ++j)
          acc[i][j] = fmaf(xs[i], bs[j], acc[i][j]);
    }
  }
  __syncthreads();

  // ---- cross-wave tree reduce (lane-major, conflict-free), then atomics ----
  float* red = smem;                    // reuse 8192 floats as red[2][4096]
  if (w >= 2) {
    #pragma unroll
    for (int i = 0; i < 8; ++i)
      #pragma unroll
      for (int j = 0; j < 8; ++j) red[(w - 2) * 4096 + (i * 8 + j) * 64 + lane] = acc[i][j];
  }
  __syncthreads();
  if (w < 2) {
    #pragma unroll
    for (int i = 0; i < 8; ++i)
      #pragma unroll
      for (int j = 0; j < 8; ++j) acc[i][j] += red[w * 4096 + (i * 8 + j) * 64 + lane];
  }
  __syncthreads();
  if (w == 1) {
    #pragma unroll
    for (int i = 0; i < 8; ++i)
      #pragma unroll
      for (int j = 0; j < 8; ++j) red[(i * 8 + j) * 64 + lane] = acc[i][j];
  }
  __syncthreads();
  if (w == 0) {
    float* op = out + (size_t)pair * 4096;
    #pragma unroll
    for (int i = 0; i < 8; ++i)
      #pragma unroll
      for (int j = 0; j < 8; ++j) {
        const float v = acc[i][j] + red[(i * 8 + j) * 64 + lane];
        atomicAdd(&op[(r * 8 + i) * 64 + c * 8 + j], v);
      }
  }
  #undef ISSUE
}

extern "C" void kernel_launch(void* const* d_in, const int* in_sizes, int n_in,
                              void* d_out, int out_size, void* d_ws, size_t ws_size,
                              hipStream_t stream) {
  const float* X = (const float*)d_in[0];   // (b, s, h, p)
  const float* A = (const float*)d_in[1];   // (b, s, h)
  const float* B = (const float*)d_in[2];   // (b, s, h, n)
  float* out = (float*)d_out;               // (b, h, p, n)

  float* Plb = (float*)d_ws;                        // 128*4096 floats = 2 MB
  float* ss  = Plb + (size_t)Bn * H * S;            // 4096 floats

  hipMemsetAsync(d_out, 0, (size_t)out_size * sizeof(float), stream);
  scanA<<<Bn * NSEG, 256, 0, stream>>>(A, Plb, ss);
  outer_k<<<Bn * H * SC, 256, 0, stream>>>(X, B, Plb, ss, out);
}

// Round 4
// 365.583 us; speedup vs baseline: 1.7796x; 1.7796x over previous
//
#include <hip/hip_runtime.h>
#include <math.h>

// out[b,h,p,n] = sum_t exp(Total(b,h) - P[t]) * X[b,t,h,p] * B[b,t,h,n]
// P = inclusive prefix sum of A over t (telescoped chunked scan; verified R1-R3).
// Shapes fixed: b=8, s=4096, h=16, p=n=64.

constexpr int Bn = 8;
constexpr int S  = 4096;
constexpr int H  = 16;
constexpr int SEG  = 128;       // prefix segment length
constexpr int NSEG = S / SEG;   // 32
constexpr int SC  = 8;          // superchunks per pair
constexpr int TPB = S / SC;     // 512 t per block
constexpr int TB  = 32;         // t per LDS stage
constexpr int NST = TPB / TB;   // 16 stages

#define AS1 __attribute__((address_space(1)))
#define AS3 __attribute__((address_space(3)))

static __device__ __forceinline__ void g2lds16(const float* g, float* l) {
  __builtin_amdgcn_global_load_lds((const AS1 unsigned int*)g, (AS3 unsigned int*)l, 16, 0, 0);
}
static __device__ __forceinline__ void g2lds4(const float* g, float* l) {
  __builtin_amdgcn_global_load_lds((const AS1 unsigned int*)g, (AS3 unsigned int*)l, 4, 0, 0);
}

// ---------- K1: per-(bb,seg) local prefix of A + segment sums (coalesced) ----------
__global__ __launch_bounds__(256) void scanA(const float* __restrict__ A,
                                             float* __restrict__ Plb,
                                             float* __restrict__ ss) {
  __shared__ float Al[SEG * 17];   // [t][h] padded
  __shared__ float sp[16][17];
  const int bb = blockIdx.x >> 5, seg = blockIdx.x & 31;
  const int tid = threadIdx.x;
  const float* src = A + ((size_t)bb * S + (size_t)seg * SEG) * H;
  #pragma unroll
  for (int k = 0; k < 2; ++k) {                 // 512 float4, coalesced
    const int f = tid + k * 256;
    const float4 v = ((const float4*)src)[f];
    const int t = f >> 2, h0 = (f & 3) * 4;
    Al[t * 17 + h0 + 0] = v.x; Al[t * 17 + h0 + 1] = v.y;
    Al[t * 17 + h0 + 2] = v.z; Al[t * 17 + h0 + 3] = v.w;
  }
  __syncthreads();
  const int h = tid >> 4, j = tid & 15;         // thread (h, j): t-strip j*8..j*8+8
  float vals[8], run = 0.f;
  #pragma unroll
  for (int k = 0; k < 8; ++k) { run += Al[(j * 8 + k) * 17 + h]; vals[k] = run; }
  sp[h][j] = run;
  __syncthreads();
  float pre = 0.f, tot = 0.f;
  #pragma unroll
  for (int jj = 0; jj < 16; ++jj) { const float x = sp[h][jj]; tot += x; if (jj < j) pre += x; }
  if (j == 0) ss[((size_t)bb * NSEG + seg) * H + h] = tot;
  float* Wp = Plb + ((size_t)(bb * H + h)) * S + seg * SEG + j * 8;
  *(float4*)(Wp)     = make_float4(pre + vals[0], pre + vals[1], pre + vals[2], pre + vals[3]);
  *(float4*)(Wp + 4) = make_float4(pre + vals[4], pre + vals[5], pre + vals[6], pre + vals[7]);
}

// ---------- K2: double-buffered staged outer-product accumulation ----------
// Block = 4 waves per (pair, superchunk). Wave w owns t-quarter (rows w*8..w*8+7
// of each 32-t stage) and accumulates the FULL 64x64 tile (8x8 per lane).
// NOTE: no min-waves pin in __launch_bounds__ — the (256,4) pin in R3 capped the
// unified VGPR/AGPR budget and spilled acc[8][8] every stage (797 MB scratch writes).
__global__ __launch_bounds__(256) void outer_k(const float* __restrict__ X,
                                               const float* __restrict__ Bm,
                                               const float* __restrict__ Plb,
                                               const float* __restrict__ ss,
                                               float* __restrict__ out) {
  // smem: Xs[2][2048] | Bs[2][2048] | Pl[2][32]   (32.25 KB)
  __shared__ float smem[4096 + 4096 + 64];
  float* Xs = smem;
  float* Bs = smem + 4096;
  float* Pl = smem + 8192;

  const int blk = blockIdx.x;
  const int pair = blk >> 3, sc = blk & 7;
  const int bb = pair >> 4, hh = pair & 15;
  const int tid = threadIdx.x, w = tid >> 6, lane = tid & 63;
  const int tstart = sc * TPB;
  const int r = lane >> 3, c = lane & 7;        // p0 = r*8, n0 = c*8

  // wave-register scan of 32 segment sums -> exclusive prefix (lane=seg) + total
  float segv = (lane < NSEG) ? ss[((size_t)bb * NSEG + lane) * H + hh] : 0.f;
  float incl = segv;
  #pragma unroll
  for (int off = 1; off < NSEG; off <<= 1) {
    const float u = __shfl_up(incl, off, 64);
    if (lane >= off) incl += u;
  }
  const float tot = __shfl(incl, NSEG - 1, 64);
  const float pe  = incl - segv;                // exclusive seg prefix (lane<32)

  constexpr size_t RS = (size_t)H * 64;         // 1024 floats per t
  const float* Xb = X  + (((size_t)bb * S + tstart) * H + hh) * 64;
  const float* Bb = Bm + (((size_t)bb * S + tstart) * H + hh) * 64;
  const float* Pb = Plb + (size_t)pair * S + tstart;

  float acc[8][8];
  #pragma unroll
  for (int i = 0; i < 8; ++i)
    #pragma unroll
    for (int j = 0; j < 8; ++j) acc[i][j] = 0.f;

  // stage issue: 16 KB (X 8KB + B 8KB). Wave w issues instrs i = 2w, 2w+1 for
  // each of X and B; instr i covers t-rows 4i..4i+3, lane-contiguous in LDS.
  #define ISSUE(s_, buf_) do {                                                  \
    const size_t sg = (size_t)(s_) * TB * RS;                                   \
    _Pragma("unroll")                                                           \
    for (int k = 0; k < 2; ++k) {                                               \
      const int i_ = w * 2 + k;                                                 \
      const size_t go = sg + (size_t)(i_ * 4 + (lane >> 4)) * RS                \
                           + (size_t)(lane & 15) * 4;                           \
      g2lds16(Xb + go, Xs + (buf_) * 2048 + i_ * 256);                          \
      g2lds16(Bb + go, Bs + (buf_) * 2048 + i_ * 256);                          \
    }                                                                           \
    if (w == 0 && lane < TB) g2lds4(Pb + (s_) * TB + lane, Pl + (buf_) * 32);   \
  } while (0)

  ISSUE(0, 0);
  for (int s = 0; s < NST; ++s) {
    __syncthreads();                    // stage s resident (prefetch had full prev stage to land)
    if (s + 1 < NST) ISSUE(s + 1, (s + 1) & 1);
    const int seg = (tstart + s * TB) >> 7;
    const float cm = tot - __shfl(pe, seg, 64);
    const float* xb = Xs + (s & 1) * 2048;
    const float* bv = Bs + (s & 1) * 2048;
    const float* pl = Pl + (s & 1) * 32;
    #pragma unroll
    for (int it = 0; it < 8; ++it) {
      const int tt = w * 8 + it;                // wave's t-quarter, contiguous
      const float wgt = __expf(cm - pl[tt]);    // exp(Total - P[t]) <= 1
      const float4 x0 = *(const float4*)(xb + tt * 64 + r * 8);
      const float4 x1 = *(const float4*)(xb + tt * 64 + r * 8 + 4);
      const float4 b0 = *(const float4*)(bv + tt * 64 + c * 8);
      const float4 b1 = *(const float4*)(bv + tt * 64 + c * 8 + 4);
      const float bs[8] = {b0.x * wgt, b0.y * wgt, b0.z * wgt, b0.w * wgt,
                           b1.x * wgt, b1.y * wgt, b1.z * wgt, b1.w * wgt};
      const float xs[8] = {x0.x, x0.y, x0.z, x0.w, x1.x, x1.y, x1.z, x1.w};
      #pragma unroll
      for (int i = 0; i < 8; ++i)
        #pragma unroll
        for (int j = 0; j < 8; ++j)
          acc[i][j] = fmaf(xs[i], bs[j], acc[i][j]);
    }
  }
  __syncthreads();

  // cross-wave tree reduce (lane-major, 2-way-bank free), then atomics to out
  float* red = smem;                    // reuse 8192 floats as red[2][4096]
  if (w >= 2) {
    #pragma unroll
    for (int i = 0; i < 8; ++i)
      #pragma unroll
      for (int j = 0; j < 8; ++j) red[(w - 2) * 4096 + (i * 8 + j) * 64 + lane] = acc[i][j];
  }
  __syncthreads();
  if (w < 2) {
    #pragma unroll
    for (int i = 0; i < 8; ++i)
      #pragma unroll
      for (int j = 0; j < 8; ++j) acc[i][j] += red[w * 4096 + (i * 8 + j) * 64 + lane];
  }
  __syncthreads();
  if (w == 1) {
    #pragma unroll
    for (int i = 0; i < 8; ++i)
      #pragma unroll
      for (int j = 0; j < 8; ++j) red[(i * 8 + j) * 64 + lane] = acc[i][j];
  }
  __syncthreads();
  if (w == 0) {
    float* op = out + (size_t)pair * 4096;
    #pragma unroll
    for (int i = 0; i < 8; ++i)
      #pragma unroll
      for (int j = 0; j < 8; ++j) {
        const float v = acc[i][j] + red[(i * 8 + j) * 64 + lane];
        atomicAdd(&op[(r * 8 + i) * 64 + c * 8 + j], v);
      }
  }
  #undef ISSUE
}

extern "C" void kernel_launch(void* const* d_in, const int* in_sizes, int n_in,
                              void* d_out, int out_size, void* d_ws, size_t ws_size,
                              hipStream_t stream) {
  const float* X = (const float*)d_in[0];   // (b, s, h, p)
  const float* A = (const float*)d_in[1];   // (b, s, h)
  const float* B = (const float*)d_in[2];   // (b, s, h, n)
  float* out = (float*)d_out;               // (b, h, p, n)

  float* Plb = (float*)d_ws;                        // 128*4096 floats = 2 MB
  float* ss  = Plb + (size_t)Bn * H * S;            // 4096 floats

  hipMemsetAsync(d_out, 0, (size_t)out_size * sizeof(float), stream);
  scanA<<<Bn * NSEG, 256, 0, stream>>>(A, Plb, ss);
  outer_k<<<Bn * H * SC, 256, 0, stream>>>(X, B, Plb, ss, out);
}